// Round 2
// baseline (2289.773 us; speedup 1.0000x reference)
//
#include <hip/hip_runtime.h>
#include <cstddef>

// Problem constants (fixed by the reference): B=4096, T=204800, D=32, H=64
#define DICE_EPS 1e-10f

// ---------------------------------------------------------------------------
// Kernel 0: segment starts from sorted row_ids.
//   seg[r] = first t with row_ids[t] >= r;  seg[B] = T.
// ---------------------------------------------------------------------------
__global__ __launch_bounds__(256) void seg_starts(const int* __restrict__ row_ids,
                                                  int* __restrict__ seg, int T, int B) {
  const int t = blockIdx.x * 256 + threadIdx.x;
  if (t >= T) return;
  const int b = row_ids[t];
  const int a = (t == 0) ? 0 : row_ids[t - 1];
  if (t == 0) seg[0] = 0;
  for (int r = a + 1; r <= b; r++) seg[r] = t;
  if (t == T - 1)
    for (int r = b + 1; r <= B; r++) seg[r] = T;
}

// ---------------------------------------------------------------------------
// Kernel 1: per-candidate precompute.
//   M[r][i][k] = W1[(32+i)*64+k] + sum_j cand[r][j] * W1[(64+i*32+j)*64+k]
// Grid = (B/8)*2: 8 candidates per block, i-range split in half across 2
// blocks -> 1024 blocks (4 blocks/CU, 16 waves/CU for latency hiding).
// ---------------------------------------------------------------------------
__global__ __launch_bounds__(256) void precompute_M(
    const float* __restrict__ cand, const float* __restrict__ W1,
    float* __restrict__ M) {
  constexpr int RT = 8;
  const int bz = blockIdx.x & 1;          // which half of the i range
  const int r0 = (blockIdx.x >> 1) * RT;  // candidate base
  __shared__ float cl[RT * 32];
  for (int idx = threadIdx.x; idx < RT * 32; idx += 256)
    cl[idx] = cand[(size_t)r0 * 32 + idx];
  __syncthreads();

  const int k = threadIdx.x & 63;  // output column
  const int q = threadIdx.x >> 6;  // wave id -> i sub-block

  float acc[4][RT];
#pragma unroll
  for (int ii = 0; ii < 4; ii++)
#pragma unroll
    for (int r = 0; r < RT; r++) acc[ii][r] = 0.f;

  for (int j = 0; j < 32; j++) {
    float cr[RT];
#pragma unroll
    for (int r = 0; r < RT; r++) cr[r] = cl[r * 32 + j];
#pragma unroll
    for (int ii = 0; ii < 4; ii++) {
      const int i = bz * 16 + q * 4 + ii;
      const float wv = W1[(size_t)(64 + i * 32 + j) * 64 + k];  // coalesced
#pragma unroll
      for (int r = 0; r < RT; r++) acc[ii][r] += cr[r] * wv;
    }
  }
#pragma unroll
  for (int ii = 0; ii < 4; ii++) {
    const int i = bz * 16 + q * 4 + ii;
    const float wb = W1[(size_t)(32 + i) * 64 + k];
#pragma unroll
    for (int r = 0; r < RT; r++)
      M[(size_t)(r0 + r) * 2048 + i * 64 + k] = acc[ii][r] + wb;
  }
}

// ---------------------------------------------------------------------------
// Kernel 2: one WAVE per candidate, one ROW per lane. Block = 4 waves = 4
// candidates. M[r] staged in LDS transposed ([k][i], stride 36 so float4
// reads stay 16B-aligned); all hot LDS reads are same-address broadcasts.
// Dice stats accumulate in-lane -> no per-row shuffles.
// ---------------------------------------------------------------------------
__global__ __launch_bounds__(256) void attention_rows(
    const float* __restrict__ cand, const float* __restrict__ behavior,
    const int* __restrict__ row_ids, const float* __restrict__ W1,
    const float* __restrict__ b1, const float* __restrict__ alpha,
    const float* __restrict__ W2, const float* __restrict__ b2,
    const float* __restrict__ M, const int* __restrict__ seg,
    float* __restrict__ out, int T) {
  const int lane = threadIdx.x & 63;
  const int wid = threadIdx.x >> 6;
  const int r = blockIdx.x * 4 + wid;

  __shared__ float Ml[4][64 * 36];  // per-wave transposed M (+ base at [k][32])
  __shared__ float alw[64], w2s[64];
  if (threadIdx.x < 64) {
    alw[threadIdx.x] = alpha[threadIdx.x];
    w2s[threadIdx.x] = W2[threadIdx.x];
  }

  float* Mw = Ml[wid];
  const float4* Mg4 = reinterpret_cast<const float4*>(M + (size_t)r * 2048);
#pragma unroll
  for (int v = 0; v < 8; v++) {
    const float4 qv = Mg4[v * 64 + lane];        // coalesced
    const int i = v * 4 + (lane >> 4);
    const int k0 = (lane & 15) * 4;
    Mw[(k0 + 0) * 36 + i] = qv.x;
    Mw[(k0 + 1) * 36 + i] = qv.y;
    Mw[(k0 + 2) * 36 + i] = qv.z;
    Mw[(k0 + 3) * 36 + i] = qv.w;
  }
  // base[k] = b1[k] + cand[r] . W1[0:32, k]   (lane k computes its own)
  float bs = b1[lane];
#pragma unroll
  for (int d = 0; d < 32; d++)
    bs += cand[(size_t)r * 32 + d] * W1[(size_t)d * 64 + lane];
  Mw[lane * 36 + 32] = bs;
  __syncthreads();

  int t0, t1;
  if (seg) {
    t0 = seg[r];
    t1 = seg[r + 1];
  } else {  // fallback: binary search (only if ws too small for seg)
    int lo = 0, hi = T;
    while (lo < hi) { int mid = (lo + hi) >> 1; if (row_ids[mid] < r) lo = mid + 1; else hi = mid; }
    t0 = lo; hi = T;
    while (lo < hi) { int mid = (lo + hi) >> 1; if (row_ids[mid] < r + 1) lo = mid + 1; else hi = mid; }
    t1 = lo;
  }

  const float b2v = b2[0];
  float acc[32];
#pragma unroll
  for (int d = 0; d < 32; d++) acc[d] = 0.f;

  for (int tb = t0; tb < t1; tb += 64) {
    const int t = tb + lane;
    float bvr[32];
    if (t < t1) {
      const float4* bp4 = reinterpret_cast<const float4*>(behavior + (size_t)t * 32);
#pragma unroll
      for (int v = 0; v < 8; v++) {
        const float4 q = bp4[v];  // one 128B line per lane, L1-hot after v=0
        bvr[4 * v + 0] = q.x; bvr[4 * v + 1] = q.y;
        bvr[4 * v + 2] = q.z; bvr[4 * v + 3] = q.w;
      }
    } else {
#pragma unroll
      for (int i = 0; i < 32; i++) bvr[i] = 0.f;  // inactive lane -> w*0
    }

    // Pass 1: h[k] for all 64 k, in-lane moment accumulation.
    float h[64];
    float s = 0.f, s2 = 0.f;
#pragma unroll
    for (int kk = 0; kk < 64; kk++) {
      const float4* m4 = reinterpret_cast<const float4*>(Mw + kk * 36);
      float p0 = Mw[kk * 36 + 32];  // base[kk] (broadcast)
      float p1 = 0.f, p2 = 0.f, p3 = 0.f;
#pragma unroll
      for (int c = 0; c < 8; c += 4) {
        const float4 m0 = m4[c + 0], m1 = m4[c + 1], m2 = m4[c + 2], m3 = m4[c + 3];
        p0 += bvr[4 * c + 0] * m0.x + bvr[4 * c + 1] * m0.y + bvr[4 * c + 2] * m0.z + bvr[4 * c + 3] * m0.w;
        p1 += bvr[4 * c + 4] * m1.x + bvr[4 * c + 5] * m1.y + bvr[4 * c + 6] * m1.z + bvr[4 * c + 7] * m1.w;
        p2 += bvr[4 * c + 8] * m2.x + bvr[4 * c + 9] * m2.y + bvr[4 * c + 10] * m2.z + bvr[4 * c + 11] * m2.w;
        p3 += bvr[4 * c + 12] * m3.x + bvr[4 * c + 13] * m3.y + bvr[4 * c + 14] * m3.z + bvr[4 * c + 15] * m3.w;
      }
      const float hv = (p0 + p1) + (p2 + p3);
      h[kk] = hv;
      s += hv;
      s2 += hv * hv;
    }

    const float mean = s * (1.f / 64.f);
    const float var = fmaxf(s2 * (1.f / 64.f) - mean * mean, 0.f);
    const float stdv = sqrtf(var + DICE_EPS);
    const float inv = __builtin_amdgcn_rcpf(stdv + DICE_EPS);

    // Pass 2: dice + H->1 projection, in-lane.
    float wp = 0.f;
#pragma unroll
    for (int kk = 0; kk < 64; kk++) {
      const float al = alw[kk];      // broadcast
      const float w2k = w2s[kk];     // broadcast
      const float dlt = h[kk] - mean;
      const float e = __expf(-dlt * inv);
      const float p = __builtin_amdgcn_rcpf(1.f + e);
      const float tt = al + p * (1.f - al);
      wp += tt * h[kk] * w2k;
    }
    const float w = wp + b2v;

#pragma unroll
    for (int d = 0; d < 32; d++) acc[d] += bvr[d] * w;  // bvr==0 if inactive
  }

  // Segment sum across the wave's 64 lanes (once per candidate).
  float res = 0.f;
#pragma unroll
  for (int d = 0; d < 32; d++) {
    float v = acc[d];
#pragma unroll
    for (int off = 32; off > 0; off >>= 1) v += __shfl_xor(v, off, 64);
    if (lane == d) res = v;
  }
  if (lane < 32) out[(size_t)r * 32 + lane] = res;
}

// ---------------------------------------------------------------------------
extern "C" void kernel_launch(void* const* d_in, const int* in_sizes, int n_in,
                              void* d_out, int out_size, void* d_ws, size_t ws_size,
                              hipStream_t stream) {
  const float* cand     = (const float*)d_in[0];
  const float* behavior = (const float*)d_in[1];
  const int*   row_ids  = (const int*)d_in[2];
  const float* W1       = (const float*)d_in[3];
  const float* b1       = (const float*)d_in[4];
  const float* alpha    = (const float*)d_in[5];
  const float* W2       = (const float*)d_in[6];
  const float* b2       = (const float*)d_in[7];
  float* out = (float*)d_out;

  const int B = in_sizes[0] / 32;  // 4096
  const int T = in_sizes[2];       // 204800

  const size_t M_bytes = (size_t)B * 2048 * sizeof(float);  // 33.5 MB
  float* M = (float*)d_ws;
  int* seg = nullptr;
  if (ws_size >= M_bytes + (size_t)(B + 1) * sizeof(int))
    seg = (int*)((char*)d_ws + M_bytes);

  if (seg) seg_starts<<<(T + 255) / 256, 256, 0, stream>>>(row_ids, seg, T, B);
  precompute_M<<<(B / 8) * 2, 256, 0, stream>>>(cand, W1, M);
  attention_rows<<<B / 4, 256, 0, stream>>>(cand, behavior, row_ids, W1, b1,
                                            alpha, W2, b2, M, seg, out, T);
}

// Round 3
// 151.712 us; speedup vs baseline: 15.0929x; 15.0929x over previous
//
#include <hip/hip_runtime.h>
#include <cstddef>

// Problem constants (fixed by the reference): B=4096, T=204800, D=32, H=64
#define DICE_EPS 1e-10f

// ---------------------------------------------------------------------------
// Kernel 0: segment starts from sorted row_ids.
//   seg[r] = first t with row_ids[t] >= r;  seg[B] = T.
// ---------------------------------------------------------------------------
__global__ __launch_bounds__(256) void seg_starts(const int* __restrict__ row_ids,
                                                  int* __restrict__ seg, int T, int B) {
  const int t = blockIdx.x * 256 + threadIdx.x;
  if (t >= T) return;
  const int b = row_ids[t];
  const int a = (t == 0) ? 0 : row_ids[t - 1];
  if (t == 0) seg[0] = 0;
  for (int r = a + 1; r <= b; r++) seg[r] = t;
  if (t == T - 1)
    for (int r = b + 1; r <= B; r++) seg[r] = T;
}

// ---------------------------------------------------------------------------
// Kernel 1: per-candidate precompute.
//   M[r][i][k] = W1[(32+i)*64+k] + sum_j cand[r][j] * W1[(64+i*32+j)*64+k]
// Grid = (B/8)*2 = 1024 blocks (4 blocks/CU, 16 waves/CU): 8 candidates per
// block, i-range split in half across 2 blocks. W1o slice re-read from L2.
// ---------------------------------------------------------------------------
__global__ __launch_bounds__(256) void precompute_M(
    const float* __restrict__ cand, const float* __restrict__ W1,
    float* __restrict__ M) {
  constexpr int RT = 8;
  const int bz = blockIdx.x & 1;          // which half of the i range
  const int r0 = (blockIdx.x >> 1) * RT;  // candidate base
  __shared__ float cl[RT * 32];
  for (int idx = threadIdx.x; idx < RT * 32; idx += 256)
    cl[idx] = cand[(size_t)r0 * 32 + idx];
  __syncthreads();

  const int k = threadIdx.x & 63;  // output column
  const int q = threadIdx.x >> 6;  // wave id -> i sub-block

  float acc[4][RT];
#pragma unroll
  for (int ii = 0; ii < 4; ii++)
#pragma unroll
    for (int r = 0; r < RT; r++) acc[ii][r] = 0.f;

  for (int j = 0; j < 32; j++) {
    float cr[RT];
#pragma unroll
    for (int r = 0; r < RT; r++) cr[r] = cl[r * 32 + j];
#pragma unroll
    for (int ii = 0; ii < 4; ii++) {
      const int i = bz * 16 + q * 4 + ii;
      const float wv = W1[(size_t)(64 + i * 32 + j) * 64 + k];  // coalesced
#pragma unroll
      for (int r = 0; r < RT; r++) acc[ii][r] += cr[r] * wv;
    }
  }
#pragma unroll
  for (int ii = 0; ii < 4; ii++) {
    const int i = bz * 16 + q * 4 + ii;
    const float wb = W1[(size_t)(32 + i) * 64 + k];
#pragma unroll
    for (int r = 0; r < RT; r++)
      M[(size_t)(r0 + r) * 2048 + i * 64 + k] = acc[ii][r] + wb;
  }
}

// ---------------------------------------------------------------------------
// Kernel 2: one block (4 waves) per candidate; wave-per-row, lane k owns h[k],
// M column in 32 VGPRs, bv broadcast via scalarized uniform loads (SGPRs).
// R=2 rows in flight per wave -> 2x independent latency chains (the R1
// bottleneck was one ~900-cyc serial chain/row at only ~5.5 waves/SIMD).
// ---------------------------------------------------------------------------
__global__ __launch_bounds__(256) void attention_rows(
    const float* __restrict__ cand, const float* __restrict__ behavior,
    const float* __restrict__ W1, const float* __restrict__ b1,
    const float* __restrict__ alpha, const float* __restrict__ W2,
    const float* __restrict__ b2, const float* __restrict__ M,
    const int* __restrict__ seg, float* __restrict__ out) {
  const int lane = threadIdx.x & 63;
  const int wid = threadIdx.x >> 6;
  const int r = blockIdx.x;

  // Per-lane constants: lane k's column of M, base[k], alpha[k], W2[k].
  float Mreg[32];
#pragma unroll
  for (int i = 0; i < 32; i++)
    Mreg[i] = M[(size_t)r * 2048 + i * 64 + lane];  // coalesced, L2/L3-hot

  float base = b1[lane];
#pragma unroll
  for (int d = 0; d < 32; d++)
    base += cand[(size_t)r * 32 + d] * W1[(size_t)d * 64 + lane];
  const float al = alpha[lane];
  const float w2k = W2[lane];
  const float b2v = b2[0];

  const int t0 = seg[r];
  const int t1 = seg[r + 1];

  float acc = 0.f;  // lane d (and d+32) accumulates out[r][d]

  for (int tb = t0; tb < t1; tb += 8) {  // block-uniform trip count
    const int ta = tb + wid * 2;
    float h[2], bvv[2], wsel[2];
    bool valid[2];

#pragma unroll
    for (int j = 0; j < 2; j++) {
      const int t = ta + j;
      valid[j] = (t < t1);
      const int tc = valid[j] ? t : (t1 - 1);            // clamped, in-bounds
      const int tu = __builtin_amdgcn_readfirstlane(tc); // wave-uniform
      const float* bp = behavior + (size_t)tu * 32;
      bvv[j] = bp[lane & 31];  // per-lane copy for the output accumulate

      // Uniform-address loads -> compiler scalarizes to s_load (R1: VGPR=32).
      float hh = base;
      const float4* b4 = reinterpret_cast<const float4*>(bp);
#pragma unroll
      for (int v = 0; v < 8; v++) {
        const float4 q = b4[v];
        hh += q.x * Mreg[4 * v + 0] + q.y * Mreg[4 * v + 1] +
              q.z * Mreg[4 * v + 2] + q.w * Mreg[4 * v + 3];
      }
      h[j] = hh;
    }

    // Combined (s, s2) butterflies, both rows interleaved: 4 independent
    // 6-stage chains the scheduler can overlap.
    float s0 = h[0], s1 = h[1];
    float q0 = h[0] * h[0], q1 = h[1] * h[1];
#pragma unroll
    for (int off = 1; off < 64; off <<= 1) {
      s0 += __shfl_xor(s0, off, 64);
      s1 += __shfl_xor(s1, off, 64);
      q0 += __shfl_xor(q0, off, 64);
      q1 += __shfl_xor(q1, off, 64);
    }
    const float sArr[2] = {s0, s1};
    const float qArr[2] = {q0, q1};

    float wp[2];
#pragma unroll
    for (int j = 0; j < 2; j++) {
      const float mean = sArr[j] * (1.f / 64.f);
      const float var = fmaxf(qArr[j] * (1.f / 64.f) - mean * mean, 0.f);
      const float stdv = sqrtf(var + DICE_EPS);
      const float inv = __builtin_amdgcn_rcpf(stdv + DICE_EPS);
      const float dlt = h[j] - mean;
      const float e = __expf(-dlt * inv);
      const float p = __builtin_amdgcn_rcpf(1.f + e);
      const float hd = (al + p * (1.f - al)) * h[j];
      wp[j] = hd * w2k;
    }
    // Two independent wp butterflies (unrolled together for ILP).
#pragma unroll
    for (int off = 1; off < 64; off <<= 1) {
      wp[0] += __shfl_xor(wp[0], off, 64);
      wp[1] += __shfl_xor(wp[1], off, 64);
    }
    wsel[0] = valid[0] ? (wp[0] + b2v) : 0.f;
    wsel[1] = valid[1] ? (wp[1] + b2v) : 0.f;

    acc = fmaf(bvv[0], wsel[0], acc);
    acc = fmaf(bvv[1], wsel[1], acc);
  }

  // Combine the 4 waves' partial segment sums through LDS.
  __shared__ float sacc[4][32];
  if (lane < 32) sacc[wid][lane] = acc;
  __syncthreads();
  if (threadIdx.x < 32) {
    out[(size_t)r * 32 + threadIdx.x] =
        sacc[0][threadIdx.x] + sacc[1][threadIdx.x] +
        sacc[2][threadIdx.x] + sacc[3][threadIdx.x];
  }
}

// ---------------------------------------------------------------------------
extern "C" void kernel_launch(void* const* d_in, const int* in_sizes, int n_in,
                              void* d_out, int out_size, void* d_ws, size_t ws_size,
                              hipStream_t stream) {
  const float* cand     = (const float*)d_in[0];
  const float* behavior = (const float*)d_in[1];
  const int*   row_ids  = (const int*)d_in[2];
  const float* W1       = (const float*)d_in[3];
  const float* b1       = (const float*)d_in[4];
  const float* alpha    = (const float*)d_in[5];
  const float* W2       = (const float*)d_in[6];
  const float* b2       = (const float*)d_in[7];
  float* out = (float*)d_out;

  const int B = in_sizes[0] / 32;  // 4096
  const int T = in_sizes[2];       // 204800

  const size_t M_bytes = (size_t)B * 2048 * sizeof(float);  // 33.5 MB
  float* M = (float*)d_ws;
  int* seg = (int*)((char*)d_ws + M_bytes);

  seg_starts<<<(T + 255) / 256, 256, 0, stream>>>(row_ids, seg, T, B);
  precompute_M<<<(B / 8) * 2, 256, 0, stream>>>(cand, W1, M);
  attention_rows<<<B, 256, 0, stream>>>(cand, behavior, W1, b1, alpha, W2, b2,
                                        M, seg, out);
}

// Round 4
// 123.831 us; speedup vs baseline: 18.4911x; 1.2252x over previous
//
#include <hip/hip_runtime.h>
#include <cstddef>

// Problem constants (fixed by the reference): B=4096, T=204800, D=32, H=64
#define DICE_EPS 1e-10f

typedef __attribute__((ext_vector_type(8))) short bf16x8;  // MFMA A/B frag
typedef __attribute__((ext_vector_type(4))) float f32x4;   // MFMA C/D frag

// Truncating fp32 -> (hi, lo) bf16 split: x ≈ hi + lo with |err| ~ 2^-17 |x|.
__device__ inline void f2bf_split(float x, short& hi, short& lo) {
  const unsigned u = __float_as_uint(x);
  hi = (short)(u >> 16);
  const float rem = x - __uint_as_float(u & 0xffff0000u);  // exact
  lo = (short)(__float_as_uint(rem) >> 16);
}

// ---------------------------------------------------------------------------
// Kernel 0: segment starts from sorted row_ids. seg[r] = first t with
// row_ids[t] >= r; seg[B] = T.
// ---------------------------------------------------------------------------
__global__ __launch_bounds__(256) void seg_starts(const int* __restrict__ row_ids,
                                                  int* __restrict__ seg, int T, int B) {
  const int t = blockIdx.x * 256 + threadIdx.x;
  if (t >= T) return;
  const int b = row_ids[t];
  const int a = (t == 0) ? 0 : row_ids[t - 1];
  if (t == 0) seg[0] = 0;
  for (int r = a + 1; r <= b; r++) seg[r] = t;
  if (t == T - 1)
    for (int r = b + 1; r <= B; r++) seg[r] = T;
}

// ---------------------------------------------------------------------------
// Kernel 1: M[r][i][k] = W1[(32+i)*64+k] + sum_j cand[r][j]*W1[(64+i*32+j)*64+k]
// 1024 blocks (4/CU). cand staged TRANSPOSED in LDS so the per-j broadcast is
// 2x ds_read_b128 instead of 8x ds_read_b32.
// ---------------------------------------------------------------------------
__global__ __launch_bounds__(256) void precompute_M(
    const float* __restrict__ cand, const float* __restrict__ W1,
    float* __restrict__ M) {
  constexpr int RT = 8;
  const int bz = blockIdx.x & 1;          // which half of the i range
  const int r0 = (blockIdx.x >> 1) * RT;  // candidate base
  __shared__ float cl_t[32 * RT];         // [j][r]
  for (int idx = threadIdx.x; idx < RT * 32; idx += 256) {
    const int r = idx >> 5, j = idx & 31;
    cl_t[j * RT + r] = cand[(size_t)r0 * 32 + idx];  // coalesced read
  }
  __syncthreads();

  const int k = threadIdx.x & 63;  // output column
  const int q = threadIdx.x >> 6;  // wave id -> i sub-block

  float acc[4][RT];
#pragma unroll
  for (int ii = 0; ii < 4; ii++)
#pragma unroll
    for (int r = 0; r < RT; r++) acc[ii][r] = 0.f;

  for (int j = 0; j < 32; j++) {
    const f32x4* c4 = reinterpret_cast<const f32x4*>(cl_t + j * RT);
    const f32x4 ca = c4[0], cb = c4[1];  // 2x broadcast ds_read_b128
    const float cr[RT] = {ca.x, ca.y, ca.z, ca.w, cb.x, cb.y, cb.z, cb.w};
#pragma unroll
    for (int ii = 0; ii < 4; ii++) {
      const int i = bz * 16 + q * 4 + ii;
      const float wv = W1[(size_t)(64 + i * 32 + j) * 64 + k];  // coalesced
#pragma unroll
      for (int r = 0; r < RT; r++) acc[ii][r] += cr[r] * wv;
    }
  }
#pragma unroll
  for (int ii = 0; ii < 4; ii++) {
    const int i = bz * 16 + q * 4 + ii;
    const float wb = W1[(size_t)(32 + i) * 64 + k];
#pragma unroll
    for (int r = 0; r < RT; r++)
      M[(size_t)(r0 + r) * 2048 + i * 64 + k] = acc[ii][r] + wb;
  }
}

// ---------------------------------------------------------------------------
// Kernel 2: one WAVE per candidate; 16 rows per MFMA tile.
//   A = bv tile (16x32), B = M_r (32x64 as 4 col-tiles), fp32 via hi/lo bf16
//   split (3 MFMAs per col-tile). C layout: col=lane&15, row=(lane>>4)*4+reg.
//   Dice stats: 4-stage butterflies within 16-lane groups (per 4 rows).
// ---------------------------------------------------------------------------
__global__ __launch_bounds__(256) void attention_mfma(
    const float* __restrict__ cand, const float* __restrict__ behavior,
    const float* __restrict__ W1, const float* __restrict__ b1,
    const float* __restrict__ alpha, const float* __restrict__ W2,
    const float* __restrict__ b2, const float* __restrict__ M,
    const int* __restrict__ seg, float* __restrict__ out) {
  const int lane = threadIdx.x & 63;
  const int wid = threadIdx.x >> 6;
  const int r = blockIdx.x * 4 + wid;  // this wave's candidate
  const int c = lane & 15;             // col-in-tile (B/C) == row m (A)
  const int g = lane >> 4;             // 16-lane group

  __shared__ float wlds[4][16];  // per-wave w[row] broadcast buffer

  const int t0 = seg[r];
  const int t1 = seg[r + 1];

  // --- B fragments: B[i][16n+c], i = 8g+j. M is [i][col] so stride 64. ---
  bf16x8 Bhi[4], Blo[4];
  {
    const float* mp = M + (size_t)r * 2048 + (size_t)(8 * g) * 64 + c;
#pragma unroll
    for (int n = 0; n < 4; n++) {
#pragma unroll
      for (int j = 0; j < 8; j++) {
        short h, l;
        f2bf_split(mp[j * 64 + 16 * n], h, l);
        Bhi[n][j] = h;
        Blo[n][j] = l;
      }
    }
  }

  // --- per-lane col constants for cols 16n+c ---
  float base_n[4], al_n[4], w2_n[4];
#pragma unroll
  for (int n = 0; n < 4; n++) {
    base_n[n] = b1[16 * n + c];
    al_n[n] = alpha[16 * n + c];
    w2_n[n] = W2[16 * n + c];
  }
  for (int d = 0; d < 32; d++) {
    const float cd = cand[(size_t)r * 32 + d];  // wave-uniform -> s_load
#pragma unroll
    for (int n = 0; n < 4; n++)
      base_n[n] = fmaf(cd, W1[(size_t)d * 64 + 16 * n + c], base_n[n]);
  }
  const float b2v = b2[0];

  float acc[8];
#pragma unroll
  for (int jj = 0; jj < 8; jj++) acc[jj] = 0.f;

  for (int tb = t0; tb < t1; tb += 16) {
    // A fragment: bv[tb+c][8g .. 8g+7] (rows >= t1 padded with 0).
    const int trow = tb + c;
    f32x4 a0 = {0.f, 0.f, 0.f, 0.f}, a1 = {0.f, 0.f, 0.f, 0.f};
    if (trow < t1) {
      const f32x4* bp =
          reinterpret_cast<const f32x4*>(behavior + (size_t)trow * 32 + 8 * g);
      a0 = bp[0];
      a1 = bp[1];
    }
    bf16x8 Ahi, Alo;
    {
      short h, l;
      f2bf_split(a0.x, h, l); Ahi[0] = h; Alo[0] = l;
      f2bf_split(a0.y, h, l); Ahi[1] = h; Alo[1] = l;
      f2bf_split(a0.z, h, l); Ahi[2] = h; Alo[2] = l;
      f2bf_split(a0.w, h, l); Ahi[3] = h; Alo[3] = l;
      f2bf_split(a1.x, h, l); Ahi[4] = h; Alo[4] = l;
      f2bf_split(a1.y, h, l); Ahi[5] = h; Alo[5] = l;
      f2bf_split(a1.z, h, l); Ahi[6] = h; Alo[6] = l;
      f2bf_split(a1.w, h, l); Ahi[7] = h; Alo[7] = l;
    }

    // C[n] = A*B[n] with hi/lo cross terms (lolo dropped).
    f32x4 C[4];
#pragma unroll
    for (int n = 0; n < 4; n++) {
      f32x4 cz = {0.f, 0.f, 0.f, 0.f};
      cz = __builtin_amdgcn_mfma_f32_16x16x32_bf16(Alo, Bhi[n], cz, 0, 0, 0);
      cz = __builtin_amdgcn_mfma_f32_16x16x32_bf16(Ahi, Blo[n], cz, 0, 0, 0);
      cz = __builtin_amdgcn_mfma_f32_16x16x32_bf16(Ahi, Bhi[n], cz, 0, 0, 0);
      C[n] = cz;
    }

    // h = C + base; raw moments per row (row = 4g+j).
    float hm[4][4];  // [reg j][tile n]
    float s[4], s2[4];
#pragma unroll
    for (int j = 0; j < 4; j++) {
      float ss = 0.f, qq = 0.f;
#pragma unroll
      for (int n = 0; n < 4; n++) {
        const float h = C[n][j] + base_n[n];
        hm[j][n] = h;
        ss += h;
        qq += h * h;
      }
      s[j] = ss;
      s2[j] = qq;
    }
#pragma unroll
    for (int off = 1; off < 16; off <<= 1) {
#pragma unroll
      for (int j = 0; j < 4; j++) {
        s[j] += __shfl_xor(s[j], off, 64);
        s2[j] += __shfl_xor(s2[j], off, 64);
      }
    }

    // Dice + H->1 projection partials.
    float wp[4];
#pragma unroll
    for (int j = 0; j < 4; j++) {
      const float mean = s[j] * (1.f / 64.f);
      const float var = fmaxf(s2[j] * (1.f / 64.f) - mean * mean, 0.f);
      const float stdv = sqrtf(var + DICE_EPS);
      const float inv = __builtin_amdgcn_rcpf(stdv + DICE_EPS);
      float w = 0.f;
#pragma unroll
      for (int n = 0; n < 4; n++) {
        const float h = hm[j][n];
        const float e = __expf((mean - h) * inv);
        const float p = __builtin_amdgcn_rcpf(1.f + e);
        const float hd = (al_n[n] + p * (1.f - al_n[n])) * h;
        w = fmaf(hd, w2_n[n], w);
      }
      wp[j] = w;
    }
#pragma unroll
    for (int off = 1; off < 16; off <<= 1) {
#pragma unroll
      for (int j = 0; j < 4; j++) wp[j] += __shfl_xor(wp[j], off, 64);
    }

    // Broadcast w[row] to the lane holding that row in the A layout (m = c).
    if (c == 0) wlds[wid][4 * g + 0] = wp[0] + b2v;
    if (c == 1) wlds[wid][4 * g + 1] = wp[1] + b2v;
    if (c == 2) wlds[wid][4 * g + 2] = wp[2] + b2v;
    if (c == 3) wlds[wid][4 * g + 3] = wp[3] + b2v;
    const float w = wlds[wid][c];  // same-wave LDS; compiler orders via lgkmcnt

    acc[0] = fmaf(a0.x, w, acc[0]);
    acc[1] = fmaf(a0.y, w, acc[1]);
    acc[2] = fmaf(a0.z, w, acc[2]);
    acc[3] = fmaf(a0.w, w, acc[3]);
    acc[4] = fmaf(a1.x, w, acc[4]);
    acc[5] = fmaf(a1.y, w, acc[5]);
    acc[6] = fmaf(a1.z, w, acc[6]);
    acc[7] = fmaf(a1.w, w, acc[7]);
  }

  // Sum over the 16 rows (lanes c=0..15 within the group), once per candidate.
#pragma unroll
  for (int off = 1; off < 16; off <<= 1) {
#pragma unroll
    for (int jj = 0; jj < 8; jj++) acc[jj] += __shfl_xor(acc[jj], off, 64);
  }
  if (c == 0) {  // lanes 0,16,32,48 -> d = 8g .. 8g+7
    f32x4 o0 = {acc[0], acc[1], acc[2], acc[3]};
    f32x4 o1 = {acc[4], acc[5], acc[6], acc[7]};
    f32x4* op = reinterpret_cast<f32x4*>(out + (size_t)r * 32 + 8 * g);
    op[0] = o0;
    op[1] = o1;
  }
}

// ---------------------------------------------------------------------------
extern "C" void kernel_launch(void* const* d_in, const int* in_sizes, int n_in,
                              void* d_out, int out_size, void* d_ws, size_t ws_size,
                              hipStream_t stream) {
  const float* cand     = (const float*)d_in[0];
  const float* behavior = (const float*)d_in[1];
  const int*   row_ids  = (const int*)d_in[2];
  const float* W1       = (const float*)d_in[3];
  const float* b1       = (const float*)d_in[4];
  const float* alpha    = (const float*)d_in[5];
  const float* W2       = (const float*)d_in[6];
  const float* b2       = (const float*)d_in[7];
  float* out = (float*)d_out;

  const int B = in_sizes[0] / 32;  // 4096
  const int T = in_sizes[2];       // 204800

  const size_t M_bytes = (size_t)B * 2048 * sizeof(float);  // 33.5 MB
  float* M = (float*)d_ws;
  int* seg = (int*)((char*)d_ws + M_bytes);

  seg_starts<<<(T + 255) / 256, 256, 0, stream>>>(row_ids, seg, T, B);
  precompute_M<<<(B / 8) * 2, 256, 0, stream>>>(cand, W1, M);
  attention_mfma<<<B / 4, 256, 0, stream>>>(cand, behavior, W1, b1, alpha, W2,
                                            b2, M, seg, out);
}